// Round 2
// baseline (592.294 us; speedup 1.0000x reference)
//
#include <hip/hip_runtime.h>
#include <hip/hip_bf16.h>
#include <stdint.h>
#include <stddef.h>

// SelfAttention: B=4 T=2048 E=1024 H=16 S=64, causal, q/k LayerNorm over S.
// Inputs/outputs are FLOAT32 (per reference setup_inputs). Compute path:
// f32 -> bf16 (RNE) at LDS-staging time, MFMA 16x16x32 bf16, f32 accumulate.
//   1) gemm_qkv: Q/K/V = x@W^T with fused per-head LayerNorm (q,k) and
//      SCALE=1/8 folded into Q.  128x128 tile, BK=32.  Writes bf16 workspace.
//   2) flash:   causal online-softmax attention, 128-row q-tiles, 64-key tiles.
//   3) gemm_bias: out = attn@Wu^T + bu  (A bf16 ws, B f32->bf16, out f32).
// Workspace: Q,K,V,AO = 4 x 16MB bf16 (64MB).

using bf16 = __hip_bfloat16;
typedef __attribute__((ext_vector_type(8))) short s16x8;
typedef __attribute__((ext_vector_type(4))) float f32x4;

#define MFMA16(a, b, c) __builtin_amdgcn_mfma_f32_16x16x32_bf16((a), (b), (c), 0, 0, 0)

static __device__ __forceinline__ s16x8 ld8(const bf16* p) {
    return *reinterpret_cast<const s16x8*>(p);
}

// load 8 f32 (two float4) and round-to-nearest-even to 8 bf16
static __device__ __forceinline__ s16x8 cvt8(const float* p) {
    f32x4 u = *reinterpret_cast<const f32x4*>(p);
    f32x4 v = *reinterpret_cast<const f32x4*>(p + 4);
    s16x8 r;
#pragma unroll
    for (int e = 0; e < 4; e++) {
        r[e]     = __builtin_bit_cast(short, __float2bfloat16(u[e]));
        r[e + 4] = __builtin_bit_cast(short, __float2bfloat16(v[e]));
    }
    return r;
}

#define EE 1024      // E = N = K of every GEMM
#define LDA 40       // LDS row stride (elems) for 32-wide K tiles (padded)

// ---------------------------------------------------------------------------
// Fused QKV GEMM + head LayerNorm.  z=0:Q(+LN,*0.125) z=1:K(+LN) z=2:V
// ---------------------------------------------------------------------------
__global__ __launch_bounds__(256) void gemm_qkv(
    const float* __restrict__ x,
    const float* __restrict__ Wq, const float* __restrict__ Wk, const float* __restrict__ Wv,
    bf16* __restrict__ Qb, bf16* __restrict__ Kb, bf16* __restrict__ Vb,
    const float* __restrict__ qg, const float* __restrict__ qbt,
    const float* __restrict__ kg, const float* __restrict__ kbt)
{
    const int z = blockIdx.z;
    const float* Bt = (z == 0) ? Wq : (z == 1) ? Wk : Wv;
    bf16* out       = (z == 0) ? Qb : (z == 1) ? Kb : Vb;
    const float* gamma = (z == 0) ? qg : kg;
    const float* beta  = (z == 0) ? qbt : kbt;
    const bool  ln     = (z < 2);
    const float oscale = (z == 0) ? 0.125f : 1.0f;   // fold softmax scale into Q

    __shared__ __align__(16) short lA[128 * LDA];
    __shared__ __align__(16) short lB[128 * LDA];

    const int tid  = threadIdx.x;
    const int lane = tid & 63;
    const int w    = tid >> 6;
    const int wr = w >> 1, wc = w & 1;       // 2x2 wave grid over 128x128 tile
    const int lr = lane & 15, quad = lane >> 4;

    const int m0 = blockIdx.y * 128;
    const int n0 = blockIdx.x * 128;

    // staging: thread -> (row = tid/2, colgroup = 16*(tid&1)) of the 128x32 tiles
    const int sr  = tid >> 1;
    const int sc0 = (tid & 1) << 4;
    const float* ap = x  + (size_t)(m0 + sr) * EE + sc0;
    const float* bp = Bt + (size_t)(n0 + sr) * EE + sc0;
    short* lap = lA + sr * LDA + sc0;
    short* lbp = lB + sr * LDA + sc0;

    f32x4 acc[4][4];
#pragma unroll
    for (int i = 0; i < 4; i++)
#pragma unroll
        for (int j = 0; j < 4; j++) acc[i][j] = (f32x4){0.f, 0.f, 0.f, 0.f};

    const short* lArd = lA + (wr * 64 + lr) * LDA + quad * 8;
    const short* lBrd = lB + (wc * 64 + lr) * LDA + quad * 8;

    for (int kt = 0; kt < EE / 32; ++kt) {
        s16x8 a0 = cvt8(ap), a1 = cvt8(ap + 8);
        s16x8 b0 = cvt8(bp), b1 = cvt8(bp + 8);
        __syncthreads();   // prior iter's ds_reads done
        *reinterpret_cast<s16x8*>(lap)     = a0;
        *reinterpret_cast<s16x8*>(lap + 8) = a1;
        *reinterpret_cast<s16x8*>(lbp)     = b0;
        *reinterpret_cast<s16x8*>(lbp + 8) = b1;
        __syncthreads();   // staging visible
        s16x8 af[4], bfr[4];
#pragma unroll
        for (int i = 0; i < 4; i++) af[i]  = *reinterpret_cast<const s16x8*>(lArd + i * 16 * LDA);
#pragma unroll
        for (int j = 0; j < 4; j++) bfr[j] = *reinterpret_cast<const s16x8*>(lBrd + j * 16 * LDA);
#pragma unroll
        for (int i = 0; i < 4; i++)
#pragma unroll
            for (int j = 0; j < 4; j++) acc[i][j] = MFMA16(af[i], bfr[j], acc[i][j]);
        ap += 32;
        bp += 32;
    }

    // epilogue: C/D layout col = lane&15, row = quad*4 + r
    if (ln) {
        float g[4], bt[4];
#pragma unroll
        for (int j = 0; j < 4; j++) {
            g[j]  = gamma[j * 16 + lr];   // s = j*16+lr (wave owns a full head)
            bt[j] = beta[j * 16 + lr];
        }
#pragma unroll
        for (int i = 0; i < 4; i++) {
#pragma unroll
            for (int r = 0; r < 4; r++) {
                float s1 = 0.f, s2 = 0.f;
#pragma unroll
                for (int j = 0; j < 4; j++) {
                    float v = acc[i][j][r];
                    s1 += v;
                    s2 += v * v;
                }
#pragma unroll
                for (int off = 1; off < 16; off <<= 1) {
                    s1 += __shfl_xor(s1, off);
                    s2 += __shfl_xor(s2, off);
                }
                float mu  = s1 * (1.f / 64.f);
                float var = s2 * (1.f / 64.f) - mu * mu;
                float rs  = rsqrtf(var + 1e-5f);
                int row = m0 + wr * 64 + i * 16 + quad * 4 + r;
#pragma unroll
                for (int j = 0; j < 4; j++) {
                    float v = ((acc[i][j][r] - mu) * rs * g[j] + bt[j]) * oscale;
                    out[(size_t)row * EE + n0 + wc * 64 + j * 16 + lr] = __float2bfloat16(v);
                }
            }
        }
    } else {
#pragma unroll
        for (int i = 0; i < 4; i++)
#pragma unroll
            for (int r = 0; r < 4; r++) {
                int row = m0 + wr * 64 + i * 16 + quad * 4 + r;
#pragma unroll
                for (int j = 0; j < 4; j++)
                    out[(size_t)row * EE + n0 + wc * 64 + j * 16 + lr] =
                        __float2bfloat16(acc[i][j][r]);
            }
    }
}

// ---------------------------------------------------------------------------
// Causal flash attention.  grid = (16 q-tiles, 64 b*h).  Block: 4 waves,
// wave w owns 32 query rows.  Scores already include 1/sqrt(S) via Q.
// ---------------------------------------------------------------------------
__global__ __launch_bounds__(256) void flash(
    const bf16* __restrict__ Qb, const bf16* __restrict__ Kb,
    const bf16* __restrict__ Vb, bf16* __restrict__ Ob)
{
    const int qt = blockIdx.x;
    const int bh = blockIdx.y;
    const int b = bh >> 4, h = bh & 15;
    const int tid = threadIdx.x, lane = tid & 63, w = tid >> 6;
    const int lr = lane & 15, quad = lane >> 4;
    const size_t base = ((size_t)(b * 2048)) * 1024 + h * 64;  // + t*1024 + s
    const int t0 = qt * 128;
    const int tw = t0 + w * 32;

    __shared__ __align__(16) short VT[64 * 72];    // V^T tile, stride 72
    __shared__ __align__(16) short PT[128 * 72];   // P tile (C-layout -> A-layout)
    bf16* VTb = reinterpret_cast<bf16*>(VT);
    bf16* PTb = reinterpret_cast<bf16*>(PT);

    // Q fragments, register-resident across the K loop
    s16x8 qf[2][2];
#pragma unroll
    for (int i = 0; i < 2; i++)
#pragma unroll
        for (int ks = 0; ks < 2; ks++)
            qf[i][ks] = ld8(Qb + base + (size_t)(tw + i * 16 + lr) * 1024 + ks * 32 + quad * 8);

    f32x4 o[2][4];
    float mrow[2][4], lrow[2][4];
#pragma unroll
    for (int i = 0; i < 2; i++) {
#pragma unroll
        for (int j = 0; j < 4; j++) o[i][j] = (f32x4){0.f, 0.f, 0.f, 0.f};
#pragma unroll
        for (int r = 0; r < 4; r++) {
            mrow[i][r] = -1e30f;
            lrow[i][r] = 0.f;
        }
    }

    const int vr = tid >> 3;   // 0..31
    const int vg = tid & 7;    // 0..7
    const float C = 1.44269504088896340736f;  // log2(e); 1/8 already folded into Q

    const int nkt = 2 * qt + 2;
    for (int kt = 0; kt < nkt; ++kt) {
        const int kb = kt * 64;
        const bool active = (kb <= tw + 31);   // wave has any unmasked key here

        // V tile (always: shared by all waves)
        s16x8 v0 = ld8(Vb + base + (size_t)(kb + vr) * 1024 + vg * 8);
        s16x8 v1 = ld8(Vb + base + (size_t)(kb + vr + 32) * 1024 + vg * 8);

        s16x8 kf[4][2];
        if (active) {
#pragma unroll
            for (int j = 0; j < 4; j++)
#pragma unroll
                for (int ks = 0; ks < 2; ks++)
                    kf[j][ks] = ld8(Kb + base + (size_t)(kb + j * 16 + lr) * 1024 +
                                    ks * 32 + quad * 8);
        }

        __syncthreads();   // prior iter's VT/PT reads done
#pragma unroll
        for (int e = 0; e < 8; e++) {          // VT[s][key] = V[key][s]
            VT[(vg * 8 + e) * 72 + vr]      = v0[e];
            VT[(vg * 8 + e) * 72 + vr + 32] = v1[e];
        }

        if (active) {
            f32x4 sc[2][4];
#pragma unroll
            for (int i = 0; i < 2; i++)
#pragma unroll
                for (int j = 0; j < 4; j++) sc[i][j] = (f32x4){0.f, 0.f, 0.f, 0.f};
#pragma unroll
            for (int ks = 0; ks < 2; ks++)
#pragma unroll
                for (int i = 0; i < 2; i++)
#pragma unroll
                    for (int j = 0; j < 4; j++)
                        sc[i][j] = MFMA16(qf[i][ks], kf[j][ks], sc[i][j]);

            const bool needmask = (kb + 63 > tw);
#pragma unroll
            for (int i = 0; i < 2; i++)
#pragma unroll
                for (int j = 0; j < 4; j++)
#pragma unroll
                    for (int r = 0; r < 4; r++) {
                        float zv = sc[i][j][r] * C;
                        if (needmask) {
                            int key = kb + j * 16 + lr;
                            int row = tw + i * 16 + quad * 4 + r;
                            if (key > row) zv = -1e30f;
                        }
                        sc[i][j][r] = zv;
                    }

            // online softmax (exp2 domain); stats per (i,r), same across 16 lanes
#pragma unroll
            for (int i = 0; i < 2; i++)
#pragma unroll
                for (int r = 0; r < 4; r++) {
                    float mx = fmaxf(fmaxf(sc[i][0][r], sc[i][1][r]),
                                     fmaxf(sc[i][2][r], sc[i][3][r]));
#pragma unroll
                    for (int off = 1; off < 16; off <<= 1) mx = fmaxf(mx, __shfl_xor(mx, off));
                    float mn    = fmaxf(mrow[i][r], mx);
                    float alpha = exp2f(mrow[i][r] - mn);
                    mrow[i][r]  = mn;
                    float ps = 0.f;
#pragma unroll
                    for (int j = 0; j < 4; j++) {
                        float pv = exp2f(sc[i][j][r] - mn);
                        sc[i][j][r] = pv;
                        ps += pv;
                    }
#pragma unroll
                    for (int off = 1; off < 16; off <<= 1) ps += __shfl_xor(ps, off);
                    lrow[i][r] = lrow[i][r] * alpha + ps;
#pragma unroll
                    for (int j = 0; j < 4; j++) o[i][j][r] *= alpha;
                }

            // P: C-layout -> LDS (row-major) for A-operand reads
#pragma unroll
            for (int i = 0; i < 2; i++)
#pragma unroll
                for (int j = 0; j < 4; j++)
#pragma unroll
                    for (int r = 0; r < 4; r++)
                        PTb[(w * 32 + i * 16 + quad * 4 + r) * 72 + j * 16 + lr] =
                            __float2bfloat16(sc[i][j][r]);
        }

        __syncthreads();   // VT + PT ready

        if (active) {
#pragma unroll
            for (int ks = 0; ks < 2; ks++) {
                s16x8 pf[2], vf[4];
#pragma unroll
                for (int i = 0; i < 2; i++)
                    pf[i] = ld8(PTb + (w * 32 + i * 16 + lr) * 72 + ks * 32 + quad * 8);
#pragma unroll
                for (int j = 0; j < 4; j++)
                    vf[j] = ld8(VTb + (j * 16 + lr) * 72 + ks * 32 + quad * 8);
#pragma unroll
                for (int i = 0; i < 2; i++)
#pragma unroll
                    for (int j = 0; j < 4; j++) o[i][j] = MFMA16(pf[i], vf[j], o[i][j]);
            }
        }
    }

    // normalize + store (bf16 workspace)
#pragma unroll
    for (int i = 0; i < 2; i++)
#pragma unroll
        for (int r = 0; r < 4; r++) {
            float inv = 1.f / lrow[i][r];
            int t = tw + i * 16 + quad * 4 + r;
#pragma unroll
            for (int j = 0; j < 4; j++)
                Ob[base + (size_t)t * 1024 + j * 16 + lr] =
                    __float2bfloat16(o[i][j][r] * inv);
        }
}

// ---------------------------------------------------------------------------
// out = A @ Wu^T + bu   (A bf16 workspace, Wu/bu f32, out f32)
// ---------------------------------------------------------------------------
__global__ __launch_bounds__(256) void gemm_bias(
    const bf16* __restrict__ A, const float* __restrict__ Bt,
    const float* __restrict__ bias, float* __restrict__ out)
{
    __shared__ __align__(16) short lA[128 * LDA];
    __shared__ __align__(16) short lB[128 * LDA];

    const int tid  = threadIdx.x;
    const int lane = tid & 63;
    const int w    = tid >> 6;
    const int wr = w >> 1, wc = w & 1;
    const int lr = lane & 15, quad = lane >> 4;

    const int m0 = blockIdx.y * 128;
    const int n0 = blockIdx.x * 128;

    const int sr  = tid >> 1;
    const int sc0 = (tid & 1) << 4;
    const bf16*  ap = A  + (size_t)(m0 + sr) * EE + sc0;
    const float* bp = Bt + (size_t)(n0 + sr) * EE + sc0;
    short* lap = lA + sr * LDA + sc0;
    short* lbp = lB + sr * LDA + sc0;

    f32x4 acc[4][4];
#pragma unroll
    for (int i = 0; i < 4; i++)
#pragma unroll
        for (int j = 0; j < 4; j++) acc[i][j] = (f32x4){0.f, 0.f, 0.f, 0.f};

    const short* lArd = lA + (wr * 64 + lr) * LDA + quad * 8;
    const short* lBrd = lB + (wc * 64 + lr) * LDA + quad * 8;

    for (int kt = 0; kt < EE / 32; ++kt) {
        s16x8 a0 = ld8(ap), a1 = ld8(ap + 8);
        s16x8 b0 = cvt8(bp), b1 = cvt8(bp + 8);
        __syncthreads();
        *reinterpret_cast<s16x8*>(lap)     = a0;
        *reinterpret_cast<s16x8*>(lap + 8) = a1;
        *reinterpret_cast<s16x8*>(lbp)     = b0;
        *reinterpret_cast<s16x8*>(lbp + 8) = b1;
        __syncthreads();
        s16x8 af[4], bfr[4];
#pragma unroll
        for (int i = 0; i < 4; i++) af[i]  = *reinterpret_cast<const s16x8*>(lArd + i * 16 * LDA);
#pragma unroll
        for (int j = 0; j < 4; j++) bfr[j] = *reinterpret_cast<const s16x8*>(lBrd + j * 16 * LDA);
#pragma unroll
        for (int i = 0; i < 4; i++)
#pragma unroll
            for (int j = 0; j < 4; j++) acc[i][j] = MFMA16(af[i], bfr[j], acc[i][j]);
        ap += 32;
        bp += 32;
    }

    float bz[4];
#pragma unroll
    for (int j = 0; j < 4; j++)
        bz[j] = bias[n0 + wc * 64 + j * 16 + lr];
#pragma unroll
    for (int i = 0; i < 4; i++)
#pragma unroll
        for (int r = 0; r < 4; r++) {
            int row = m0 + wr * 64 + i * 16 + quad * 4 + r;
#pragma unroll
            for (int j = 0; j < 4; j++)
                out[(size_t)row * EE + n0 + wc * 64 + j * 16 + lr] =
                    acc[i][j][r] + bz[j];
        }
}

// ---------------------------------------------------------------------------
extern "C" void kernel_launch(void* const* d_in, const int* in_sizes, int n_in,
                              void* d_out, int out_size, void* d_ws, size_t ws_size,
                              hipStream_t stream)
{
    (void)in_sizes; (void)n_in; (void)out_size; (void)ws_size;
    const float* x   = (const float*)d_in[0];
    const float* Wq  = (const float*)d_in[1];
    const float* Wk  = (const float*)d_in[2];
    const float* Wv  = (const float*)d_in[3];
    const float* Wu  = (const float*)d_in[4];
    const float* bu  = (const float*)d_in[5];
    const float* qg  = (const float*)d_in[6];
    const float* qbt = (const float*)d_in[7];
    const float* kg  = (const float*)d_in[8];
    const float* kbt = (const float*)d_in[9];
    float* out = (float*)d_out;

    bf16* Qb = (bf16*)d_ws;
    bf16* Kb = Qb + (size_t)8192 * 1024;
    bf16* Vb = Kb + (size_t)8192 * 1024;
    bf16* AO = Vb + (size_t)8192 * 1024;

    gemm_qkv<<<dim3(8, 64, 3), 256, 0, stream>>>(x, Wq, Wk, Wv, Qb, Kb, Vb, qg, qbt, kg, kbt);
    flash<<<dim3(16, 64), 256, 0, stream>>>(Qb, Kb, Vb, AO);
    gemm_bias<<<dim3(8, 64), 256, 0, stream>>>(AO, Wu, bu, out);
}

// Round 3
// 405.433 us; speedup vs baseline: 1.4609x; 1.4609x over previous
//
#include <hip/hip_runtime.h>
#include <hip/hip_bf16.h>
#include <stdint.h>
#include <stddef.h>

// SelfAttention: B=4 T=2048 E=1024 H=16 S=64, causal, q/k LayerNorm over S.
// f32 in/out; bf16 MFMA compute.
//   0) cvtw: Wq/Wk/Wv/Wu f32 -> bf16 (one pass).
//   1) gemm_qkv: Q/K/V = x@W^T, fused head-LayerNorm (q,k), SCALE folded in Q.
//   2) flash: causal online-softmax attention, S^T=K*Q^T orientation so the
//      key-reduction is in-register + 2-step quad butterfly (not 4-step lr
//      butterfly).  Block = balanced q-tile pair (p, 15-p): 34 k-tiles each.
//      Output aliases Qb (safe: Q rows are register-read before O write).
//   3) gemm_bias: out = attn@Wu^T + bu.
// Workspace: Q(=AO),K,V bf16 (48MB) + W bf16 (8MB) = 56MB.

using bf16 = __hip_bfloat16;
typedef __attribute__((ext_vector_type(8))) short s16x8;
typedef __attribute__((ext_vector_type(4))) short s16x4;
typedef __attribute__((ext_vector_type(4))) float f32x4;

#define MFMA16(a, b, c) __builtin_amdgcn_mfma_f32_16x16x32_bf16((a), (b), (c), 0, 0, 0)

static __device__ __forceinline__ s16x8 ld8(const bf16* p) {
    return *reinterpret_cast<const s16x8*>(p);
}
static __device__ __forceinline__ s16x8 ld8s(const short* p) {
    return *reinterpret_cast<const s16x8*>(p);
}
static __device__ __forceinline__ s16x8 cvt8(const float* p) {
    f32x4 u = *reinterpret_cast<const f32x4*>(p);
    f32x4 v = *reinterpret_cast<const f32x4*>(p + 4);
    s16x8 r;
#pragma unroll
    for (int e = 0; e < 4; e++) {
        r[e]     = __builtin_bit_cast(short, __float2bfloat16(u[e]));
        r[e + 4] = __builtin_bit_cast(short, __float2bfloat16(v[e]));
    }
    return r;
}

#define EE 1024
#define LDA 40

// ---------------------------------------------------------------------------
// Weight f32 -> bf16 (4 x 1M elems)
// ---------------------------------------------------------------------------
__global__ __launch_bounds__(256) void cvtw(
    const float* __restrict__ w0, const float* __restrict__ w1,
    const float* __restrict__ w2, const float* __restrict__ w3,
    bf16* __restrict__ o0, bf16* __restrict__ o1,
    bf16* __restrict__ o2, bf16* __restrict__ o3)
{
    const float* s = (blockIdx.z == 0) ? w0 : (blockIdx.z == 1) ? w1
                   : (blockIdx.z == 2) ? w2 : w3;
    bf16* d        = (blockIdx.z == 0) ? o0 : (blockIdx.z == 1) ? o1
                   : (blockIdx.z == 2) ? o2 : o3;
    size_t i = ((size_t)blockIdx.x * 256 + threadIdx.x) * 8;
    *reinterpret_cast<s16x8*>(d + i) = cvt8(s + i);
}

// ---------------------------------------------------------------------------
// Fused QKV GEMM + head LayerNorm.  z=0:Q(+LN,*0.125) z=1:K(+LN) z=2:V
// A = x (f32, cvt at stage), B = W bf16 (pre-converted).
// ---------------------------------------------------------------------------
__global__ __launch_bounds__(256) void gemm_qkv(
    const float* __restrict__ x,
    const bf16* __restrict__ Wq, const bf16* __restrict__ Wk, const bf16* __restrict__ Wv,
    bf16* __restrict__ Qb, bf16* __restrict__ Kb, bf16* __restrict__ Vb,
    const float* __restrict__ qg, const float* __restrict__ qbt,
    const float* __restrict__ kg, const float* __restrict__ kbt)
{
    const int z = blockIdx.z;
    const bf16* Bt = (z == 0) ? Wq : (z == 1) ? Wk : Wv;
    bf16* out      = (z == 0) ? Qb : (z == 1) ? Kb : Vb;
    const float* gamma = (z == 0) ? qg : kg;
    const float* beta  = (z == 0) ? qbt : kbt;
    const bool  ln     = (z < 2);
    const float oscale = (z == 0) ? 0.125f : 1.0f;

    __shared__ __align__(16) short lA[128 * LDA];
    __shared__ __align__(16) short lB[128 * LDA];

    const int tid  = threadIdx.x;
    const int lane = tid & 63;
    const int w    = tid >> 6;
    const int wr = w >> 1, wc = w & 1;
    const int lr = lane & 15, quad = lane >> 4;

    const int m0 = blockIdx.y * 128;
    const int n0 = blockIdx.x * 128;

    const int sr  = tid >> 1;
    const int sc0 = (tid & 1) << 4;
    const float* ap = x  + (size_t)(m0 + sr) * EE + sc0;
    const bf16*  bp = Bt + (size_t)(n0 + sr) * EE + sc0;
    short* lap = lA + sr * LDA + sc0;
    short* lbp = lB + sr * LDA + sc0;

    f32x4 acc[4][4];
#pragma unroll
    for (int i = 0; i < 4; i++)
#pragma unroll
        for (int j = 0; j < 4; j++) acc[i][j] = (f32x4){0.f, 0.f, 0.f, 0.f};

    const short* lArd = lA + (wr * 64 + lr) * LDA + quad * 8;
    const short* lBrd = lB + (wc * 64 + lr) * LDA + quad * 8;

    for (int kt = 0; kt < EE / 32; ++kt) {
        s16x8 a0 = cvt8(ap), a1 = cvt8(ap + 8);
        s16x8 b0 = ld8(bp),  b1 = ld8(bp + 8);
        __syncthreads();
        *reinterpret_cast<s16x8*>(lap)     = a0;
        *reinterpret_cast<s16x8*>(lap + 8) = a1;
        *reinterpret_cast<s16x8*>(lbp)     = b0;
        *reinterpret_cast<s16x8*>(lbp + 8) = b1;
        __syncthreads();
        s16x8 af[4], bfr[4];
#pragma unroll
        for (int i = 0; i < 4; i++) af[i]  = ld8s(lArd + i * 16 * LDA);
#pragma unroll
        for (int j = 0; j < 4; j++) bfr[j] = ld8s(lBrd + j * 16 * LDA);
#pragma unroll
        for (int i = 0; i < 4; i++)
#pragma unroll
            for (int j = 0; j < 4; j++) acc[i][j] = MFMA16(af[i], bfr[j], acc[i][j]);
        ap += 32;
        bp += 32;
    }

    if (ln) {
        float g[4], bt[4];
#pragma unroll
        for (int j = 0; j < 4; j++) {
            g[j]  = gamma[j * 16 + lr];
            bt[j] = beta[j * 16 + lr];
        }
#pragma unroll
        for (int i = 0; i < 4; i++) {
#pragma unroll
            for (int r = 0; r < 4; r++) {
                float s1 = 0.f, s2 = 0.f;
#pragma unroll
                for (int j = 0; j < 4; j++) {
                    float v = acc[i][j][r];
                    s1 += v;
                    s2 += v * v;
                }
#pragma unroll
                for (int off = 1; off < 16; off <<= 1) {
                    s1 += __shfl_xor(s1, off);
                    s2 += __shfl_xor(s2, off);
                }
                float mu  = s1 * (1.f / 64.f);
                float var = s2 * (1.f / 64.f) - mu * mu;
                float rs  = rsqrtf(var + 1e-5f);
                int row = m0 + wr * 64 + i * 16 + quad * 4 + r;
#pragma unroll
                for (int j = 0; j < 4; j++) {
                    float v = ((acc[i][j][r] - mu) * rs * g[j] + bt[j]) * oscale;
                    out[(size_t)row * EE + n0 + wc * 64 + j * 16 + lr] = __float2bfloat16(v);
                }
            }
        }
    } else {
#pragma unroll
        for (int i = 0; i < 4; i++)
#pragma unroll
            for (int r = 0; r < 4; r++) {
                int row = m0 + wr * 64 + i * 16 + quad * 4 + r;
#pragma unroll
                for (int j = 0; j < 4; j++)
                    out[(size_t)row * EE + n0 + wc * 64 + j * 16 + lr] =
                        __float2bfloat16(acc[i][j][r]);
            }
    }
}

// ---------------------------------------------------------------------------
// Causal flash attention, transposed-score orientation.
// grid = (8 pairs, 64 b*h); block = 4 waves; wave owns 32 q-rows per tile.
// Per block: q-tiles {p, 15-p} -> exactly 34 k-tiles of work.
// ---------------------------------------------------------------------------
__global__ __launch_bounds__(256) void flash(
    const bf16* __restrict__ Qb, const bf16* __restrict__ Kb,
    const bf16* __restrict__ Vb, bf16* __restrict__ Ob)
{
    const int pr = blockIdx.x;
    const int bh = blockIdx.y;
    const int b = bh >> 4, h = bh & 15;
    const int tid = threadIdx.x, lane = tid & 63, w = tid >> 6;
    const int lr = lane & 15, quad = lane >> 4;
    const size_t base = (size_t)b * 2048 * 1024 + h * 64;
    const float C = 1.44269504088896340736f;   // log2(e); 1/8 folded into Q

    __shared__ __align__(16) short VT[64 * 72];    // V^T tile [s][key]
    __shared__ __align__(16) short PT[128 * 72];   // P tile   [query][key]

#pragma unroll 1
    for (int ph = 0; ph < 2; ++ph) {
        const int qt = ph ? (15 - pr) : pr;
        const int tw = qt * 128 + w * 32;

        // Q fragments (B operand: col=query=lr, k=quad*8)
        s16x8 qf[2][2];
#pragma unroll
        for (int i = 0; i < 2; i++)
#pragma unroll
            for (int ks = 0; ks < 2; ks++)
                qf[i][ks] = ld8(Qb + base + (size_t)(tw + i * 16 + lr) * 1024 +
                                ks * 32 + quad * 8);

        f32x4 o[2][4];
        float mrow[2], lrow[2];
#pragma unroll
        for (int i = 0; i < 2; i++) {
#pragma unroll
            for (int j = 0; j < 4; j++) o[i][j] = (f32x4){0.f, 0.f, 0.f, 0.f};
            mrow[i] = -1e30f;
            lrow[i] = 0.f;
        }

        const int nkt = 2 * qt + 2;
        for (int kt = 0; kt < nkt; ++kt) {
            const int kb = kt * 64;
            const bool active = (kb <= tw + 31);

            // V tile: lane=key, wave=s-group (conflict-free VT writes)
            s16x8 v0 = ld8(Vb + base + (size_t)(kb + lane) * 1024 + w * 8);
            s16x8 v1 = ld8(Vb + base + (size_t)(kb + lane) * 1024 + w * 8 + 32);

            // K fragments (A operand: row=key=lr, k=quad*8)
            s16x8 kf[4][2];
            if (active) {
#pragma unroll
                for (int jk = 0; jk < 4; jk++)
#pragma unroll
                    for (int ks = 0; ks < 2; ks++)
                        kf[jk][ks] = ld8(Kb + base + (size_t)(kb + jk * 16 + lr) * 1024 +
                                         ks * 32 + quad * 8);
            }

            __syncthreads();   // prior iter's VT/PT reads done
#pragma unroll
            for (int e = 0; e < 8; e++) {
                VT[(w * 8 + e) * 72 + lane]        = v0[e];
                VT[(w * 8 + 32 + e) * 72 + lane]   = v1[e];
            }

            float a_bc[2][4];
            if (active) {
                // S^T = K*Q^T: row=key=quad*4+r (subtile jk), col=query=lr (grp i)
                f32x4 sc[2][4];
#pragma unroll
                for (int i = 0; i < 2; i++)
#pragma unroll
                    for (int jk = 0; jk < 4; jk++) sc[i][jk] = (f32x4){0.f, 0.f, 0.f, 0.f};
#pragma unroll
                for (int ks = 0; ks < 2; ks++)
#pragma unroll
                    for (int i = 0; i < 2; i++)
#pragma unroll
                        for (int jk = 0; jk < 4; jk++)
                            sc[i][jk] = MFMA16(kf[jk][ks], qf[i][ks], sc[i][jk]);

#pragma unroll
                for (int i = 0; i < 2; i++) {
                    const int qq = tw + i * 16 + lr;
                    float mx = -1e30f;
#pragma unroll
                    for (int jk = 0; jk < 4; jk++)
#pragma unroll
                        for (int r = 0; r < 4; r++) {
                            float zv = sc[i][jk][r] * C;
                            int key = kb + jk * 16 + quad * 4 + r;
                            if (key > qq) zv = -1e30f;
                            sc[i][jk][r] = zv;
                            mx = fmaxf(mx, zv);
                        }
                    mx = fmaxf(mx, __shfl_xor(mx, 16));
                    mx = fmaxf(mx, __shfl_xor(mx, 32));
                    float mn = fmaxf(mrow[i], mx);
                    float al = exp2f(mrow[i] - mn);
                    mrow[i] = mn;
                    float ps = 0.f;
#pragma unroll
                    for (int jk = 0; jk < 4; jk++)
#pragma unroll
                        for (int r = 0; r < 4; r++) {
                            float pv = exp2f(sc[i][jk][r] - mn);
                            sc[i][jk][r] = pv;
                            ps += pv;
                        }
                    ps += __shfl_xor(ps, 16);
                    ps += __shfl_xor(ps, 32);
                    lrow[i] = lrow[i] * al + ps;

                    // P[query][key]: 4 consecutive keys per reg -> b64 writes
                    short* prow = PT + (w * 32 + i * 16 + lr) * 72;
#pragma unroll
                    for (int jk = 0; jk < 4; jk++) {
                        s16x4 pk;
#pragma unroll
                        for (int r = 0; r < 4; r++)
                            pk[r] = __builtin_bit_cast(short, __float2bfloat16(sc[i][jk][r]));
                        *reinterpret_cast<s16x4*>(prow + jk * 16 + quad * 4) = pk;
                    }
                    // broadcast alpha to O-row layout (row=quad*4+r)
#pragma unroll
                    for (int r = 0; r < 4; r++) a_bc[i][r] = __shfl(al, quad * 4 + r);
                }
            }

            __syncthreads();   // VT + PT ready

            if (active) {
#pragma unroll
                for (int i = 0; i < 2; i++)
#pragma unroll
                    for (int j = 0; j < 4; j++)
#pragma unroll
                        for (int r = 0; r < 4; r++) o[i][j][r] *= a_bc[i][r];
#pragma unroll
                for (int ks = 0; ks < 2; ks++) {
                    s16x8 pf[2], vf[4];
#pragma unroll
                    for (int i = 0; i < 2; i++)
                        pf[i] = ld8s(PT + (w * 32 + i * 16 + lr) * 72 + ks * 32 + quad * 8);
#pragma unroll
                    for (int j = 0; j < 4; j++)
                        vf[j] = ld8s(VT + (j * 16 + lr) * 72 + ks * 32 + quad * 8);
#pragma unroll
                    for (int i = 0; i < 2; i++)
#pragma unroll
                        for (int j = 0; j < 4; j++) o[i][j] = MFMA16(pf[i], vf[j], o[i][j]);
                }
            }
        }

        // epilogue: broadcast l to O-row layout, normalize, store
#pragma unroll
        for (int i = 0; i < 2; i++) {
            float lb[4];
#pragma unroll
            for (int r = 0; r < 4; r++) lb[r] = __shfl(lrow[i], quad * 4 + r);
#pragma unroll
            for (int r = 0; r < 4; r++) {
                float inv = 1.f / lb[r];
                int t = tw + i * 16 + quad * 4 + r;
#pragma unroll
                for (int j = 0; j < 4; j++)
                    Ob[base + (size_t)t * 1024 + j * 16 + lr] =
                        __float2bfloat16(o[i][j][r] * inv);
            }
        }
    }
}

// ---------------------------------------------------------------------------
// out = A @ Wu^T + bu   (A bf16 ws, Wu bf16 ws, bu f32, out f32)
// ---------------------------------------------------------------------------
__global__ __launch_bounds__(256) void gemm_bias(
    const bf16* __restrict__ A, const bf16* __restrict__ Bt,
    const float* __restrict__ bias, float* __restrict__ out)
{
    __shared__ __align__(16) short lA[128 * LDA];
    __shared__ __align__(16) short lB[128 * LDA];

    const int tid  = threadIdx.x;
    const int lane = tid & 63;
    const int w    = tid >> 6;
    const int wr = w >> 1, wc = w & 1;
    const int lr = lane & 15, quad = lane >> 4;

    const int m0 = blockIdx.y * 128;
    const int n0 = blockIdx.x * 128;

    const int sr  = tid >> 1;
    const int sc0 = (tid & 1) << 4;
    const bf16* ap = A  + (size_t)(m0 + sr) * EE + sc0;
    const bf16* bp = Bt + (size_t)(n0 + sr) * EE + sc0;
    short* lap = lA + sr * LDA + sc0;
    short* lbp = lB + sr * LDA + sc0;

    f32x4 acc[4][4];
#pragma unroll
    for (int i = 0; i < 4; i++)
#pragma unroll
        for (int j = 0; j < 4; j++) acc[i][j] = (f32x4){0.f, 0.f, 0.f, 0.f};

    const short* lArd = lA + (wr * 64 + lr) * LDA + quad * 8;
    const short* lBrd = lB + (wc * 64 + lr) * LDA + quad * 8;

    for (int kt = 0; kt < EE / 32; ++kt) {
        s16x8 a0 = ld8(ap), a1 = ld8(ap + 8);
        s16x8 b0 = ld8(bp), b1 = ld8(bp + 8);
        __syncthreads();
        *reinterpret_cast<s16x8*>(lap)     = a0;
        *reinterpret_cast<s16x8*>(lap + 8) = a1;
        *reinterpret_cast<s16x8*>(lbp)     = b0;
        *reinterpret_cast<s16x8*>(lbp + 8) = b1;
        __syncthreads();
        s16x8 af[4], bfr[4];
#pragma unroll
        for (int i = 0; i < 4; i++) af[i]  = ld8s(lArd + i * 16 * LDA);
#pragma unroll
        for (int j = 0; j < 4; j++) bfr[j] = ld8s(lBrd + j * 16 * LDA);
#pragma unroll
        for (int i = 0; i < 4; i++)
#pragma unroll
            for (int j = 0; j < 4; j++) acc[i][j] = MFMA16(af[i], bfr[j], acc[i][j]);
        ap += 32;
        bp += 32;
    }

    float bz[4];
#pragma unroll
    for (int j = 0; j < 4; j++)
        bz[j] = bias[n0 + wc * 64 + j * 16 + lr];
#pragma unroll
    for (int i = 0; i < 4; i++)
#pragma unroll
        for (int r = 0; r < 4; r++) {
            int row = m0 + wr * 64 + i * 16 + quad * 4 + r;
#pragma unroll
            for (int j = 0; j < 4; j++)
                out[(size_t)row * EE + n0 + wc * 64 + j * 16 + lr] =
                    acc[i][j][r] + bz[j];
        }
}

// ---------------------------------------------------------------------------
extern "C" void kernel_launch(void* const* d_in, const int* in_sizes, int n_in,
                              void* d_out, int out_size, void* d_ws, size_t ws_size,
                              hipStream_t stream)
{
    (void)in_sizes; (void)n_in; (void)out_size; (void)ws_size;
    const float* x   = (const float*)d_in[0];
    const float* Wq  = (const float*)d_in[1];
    const float* Wk  = (const float*)d_in[2];
    const float* Wv  = (const float*)d_in[3];
    const float* Wu  = (const float*)d_in[4];
    const float* bu  = (const float*)d_in[5];
    const float* qg  = (const float*)d_in[6];
    const float* qbt = (const float*)d_in[7];
    const float* kg  = (const float*)d_in[8];
    const float* kbt = (const float*)d_in[9];
    float* out = (float*)d_out;

    bf16* Qb  = (bf16*)d_ws;                    // 16MB (doubles as attn-out)
    bf16* Kb  = Qb  + (size_t)8192 * 1024;
    bf16* Vb  = Kb  + (size_t)8192 * 1024;
    bf16* Wqb = Vb  + (size_t)8192 * 1024;      // 2MB each
    bf16* Wkb = Wqb + (size_t)1024 * 1024;
    bf16* Wvb = Wkb + (size_t)1024 * 1024;
    bf16* Wub = Wvb + (size_t)1024 * 1024;

    cvtw<<<dim3(512, 1, 4), 256, 0, stream>>>(Wq, Wk, Wv, Wu, Wqb, Wkb, Wvb, Wub);
    gemm_qkv<<<dim3(8, 64, 3), 256, 0, stream>>>(x, Wqb, Wkb, Wvb, Qb, Kb, Vb,
                                                 qg, qbt, kg, kbt);
    flash<<<dim3(8, 64), 256, 0, stream>>>(Qb, Kb, Vb, Qb);
    gemm_bias<<<dim3(8, 64), 256, 0, stream>>>(Qb, Wub, bu, out);
}

// Round 4
// 341.541 us; speedup vs baseline: 1.7342x; 1.1871x over previous
//
#include <hip/hip_runtime.h>
#include <hip/hip_bf16.h>
#include <stdint.h>
#include <stddef.h>

// SelfAttention: B=4 T=2048 E=1024 H=16 S=64, causal, q/k LayerNorm over S.
// f32 in/out; bf16 MFMA compute.
//   0) cvt_all: Wq/Wk/Wv/Wu and x f32 -> bf16 (one pass).
//   1) gemm_qkv: Q/K/V = x@W^T, fused head-LayerNorm (q,k), SCALE folded in Q.
//      m97 structure: global_load_lds width-16 staging, 128x128 tile, BK=32.
//   2) flash: causal online-softmax attention, S^T=K*Q^T orientation,
//      balanced q-tile pairs (p, 15-p).  Output aliases Qb.
//   3) gemm_bias: out = attn@Wu^T + bu (same m97 structure).
// Workspace: Q(=AO),K,V (48MB) + W bf16 (8MB) + xb (16MB) = 72MB (fallback
// template if ws_size < 72MB keeps the old f32-A staging).

using bf16 = __hip_bfloat16;
typedef __attribute__((ext_vector_type(8))) short s16x8;
typedef __attribute__((ext_vector_type(4))) short s16x4;
typedef __attribute__((ext_vector_type(4))) float f32x4;

#define MFMA16(a, b, c) __builtin_amdgcn_mfma_f32_16x16x32_bf16((a), (b), (c), 0, 0, 0)

static __device__ __forceinline__ s16x8 ld8(const bf16* p) {
    return *reinterpret_cast<const s16x8*>(p);
}
static __device__ __forceinline__ s16x8 ld8s(const short* p) {
    return *reinterpret_cast<const s16x8*>(p);
}
static __device__ __forceinline__ s16x8 cvt8(const float* p) {
    f32x4 u = *reinterpret_cast<const f32x4*>(p);
    f32x4 v = *reinterpret_cast<const f32x4*>(p + 4);
    s16x8 r;
#pragma unroll
    for (int e = 0; e < 4; e++) {
        r[e]     = __builtin_bit_cast(short, __float2bfloat16(u[e]));
        r[e + 4] = __builtin_bit_cast(short, __float2bfloat16(v[e]));
    }
    return r;
}

// async global(bf16)->LDS, 16B per lane; lds base must be wave-uniform.
static __device__ __forceinline__ void async16(short* lds, const bf16* g) {
    __builtin_amdgcn_global_load_lds(
        (const __attribute__((address_space(1))) unsigned int*)g,
        (__attribute__((address_space(3))) unsigned int*)lds, 16, 0, 0);
}

#define EE 1024

// ---------------------------------------------------------------------------
// f32 -> bf16: z=0..3 weights (1M each), z=4..11 x slices (8 x 1M)
// ---------------------------------------------------------------------------
__global__ __launch_bounds__(256) void cvt_all(
    const float* __restrict__ w0, const float* __restrict__ w1,
    const float* __restrict__ w2, const float* __restrict__ w3,
    const float* __restrict__ x,
    bf16* __restrict__ o0, bf16* __restrict__ o1,
    bf16* __restrict__ o2, bf16* __restrict__ o3, bf16* __restrict__ xb)
{
    const int z = blockIdx.z;
    const float* s;
    bf16* d;
    if (z < 4) {
        s = (z == 0) ? w0 : (z == 1) ? w1 : (z == 2) ? w2 : w3;
        d = (z == 0) ? o0 : (z == 1) ? o1 : (z == 2) ? o2 : o3;
    } else {
        s = x  + (size_t)(z - 4) * 1048576;
        d = xb + (size_t)(z - 4) * 1048576;
    }
    size_t i = ((size_t)blockIdx.x * 256 + threadIdx.x) * 8;
    *reinterpret_cast<s16x8*>(d + i) = cvt8(s + i);
}

// ---------------------------------------------------------------------------
// Fused QKV GEMM + head LayerNorm.  z=0:Q(+LN,*0.125) z=1:K(+LN) z=2:V
// AF32=0: A staged via global_load_lds from xb.  AF32=1: f32 cvt fallback.
// ---------------------------------------------------------------------------
template <int AF32>
__global__ __launch_bounds__(256) void gemm_qkv_t(
    const float* __restrict__ xf, const bf16* __restrict__ xb,
    const bf16* __restrict__ Wq, const bf16* __restrict__ Wk, const bf16* __restrict__ Wv,
    bf16* __restrict__ Qb, bf16* __restrict__ Kb, bf16* __restrict__ Vb,
    const float* __restrict__ qg, const float* __restrict__ qbt,
    const float* __restrict__ kg, const float* __restrict__ kbt)
{
    constexpr int SA = AF32 ? 40 : 32;   // A-tile LDS stride (pad only in fallback)
    const int z = blockIdx.z;
    const bf16* Bt = (z == 0) ? Wq : (z == 1) ? Wk : Wv;
    bf16* out      = (z == 0) ? Qb : (z == 1) ? Kb : Vb;
    const float* gamma = (z == 0) ? qg : kg;
    const float* beta  = (z == 0) ? qbt : kbt;
    const bool  ln     = (z < 2);
    const float oscale = (z == 0) ? 0.125f : 1.0f;

    __shared__ __align__(16) short lA[128 * SA];
    __shared__ __align__(16) short lB[128 * 32];

    const int tid  = threadIdx.x;
    const int lane = tid & 63;
    const int w    = tid >> 6;
    const int wr = w >> 1, wc = w & 1;
    const int lr = lane & 15, quad = lane >> 4;

    const int m0 = blockIdx.y * 128;
    const int n0 = blockIdx.x * 128;

    // global_load_lds staging geometry: inst q covers 16 rows x 32 cols (1KB)
    const int strow = w * 32 + (lane >> 2);      // q=0 row
    const int stcol = (lane & 3) * 8;            // shorts
    const bf16* bgl = Bt + (size_t)(n0 + strow) * EE + stcol;
    short* bl = lB + (w * 2) * 512;              // wave-uniform

    const bf16* agl = nullptr;
    const float* ap = nullptr;
    short* al = lA + (w * 2) * 512;
    short* lap = nullptr;
    if constexpr (AF32) {
        const int sr  = tid >> 1;
        const int sc0 = (tid & 1) << 4;
        ap  = xf + (size_t)(m0 + sr) * EE + sc0;
        lap = lA + sr * SA + sc0;
    } else {
        agl = xb + (size_t)(m0 + strow) * EE + stcol;
    }

    f32x4 acc[4][4];
#pragma unroll
    for (int i = 0; i < 4; i++)
#pragma unroll
        for (int j = 0; j < 4; j++) acc[i][j] = (f32x4){0.f, 0.f, 0.f, 0.f};

    const short* lArd = lA + (wr * 64 + lr) * SA + quad * 8;
    const short* lBrd = lB + (wc * 64 + lr) * 32 + quad * 8;

    for (int kt = 0; kt < EE / 32; ++kt) {
        if constexpr (AF32) {
            s16x8 a0 = cvt8(ap), a1 = cvt8(ap + 8);
            __syncthreads();
            *reinterpret_cast<s16x8*>(lap)     = a0;
            *reinterpret_cast<s16x8*>(lap + 8) = a1;
            async16(bl, bgl);
            async16(bl + 512, bgl + 16 * EE);
            ap += 32;
        } else {
            __syncthreads();
            async16(al, agl);
            async16(al + 512, agl + 16 * EE);
            async16(bl, bgl);
            async16(bl + 512, bgl + 16 * EE);
            agl += 32;
        }
        bgl += 32;
        __syncthreads();

        s16x8 af[4], bfr[4];
#pragma unroll
        for (int i = 0; i < 4; i++) af[i]  = ld8s(lArd + i * 16 * SA);
#pragma unroll
        for (int j = 0; j < 4; j++) bfr[j] = ld8s(lBrd + j * 16 * 32);
#pragma unroll
        for (int i = 0; i < 4; i++)
#pragma unroll
            for (int j = 0; j < 4; j++) acc[i][j] = MFMA16(af[i], bfr[j], acc[i][j]);
    }

    if (ln) {
        float g[4], bt[4];
#pragma unroll
        for (int j = 0; j < 4; j++) {
            g[j]  = gamma[j * 16 + lr];
            bt[j] = beta[j * 16 + lr];
        }
#pragma unroll
        for (int i = 0; i < 4; i++) {
#pragma unroll
            for (int r = 0; r < 4; r++) {
                float s1 = 0.f, s2 = 0.f;
#pragma unroll
                for (int j = 0; j < 4; j++) {
                    float v = acc[i][j][r];
                    s1 += v;
                    s2 += v * v;
                }
#pragma unroll
                for (int off = 1; off < 16; off <<= 1) {
                    s1 += __shfl_xor(s1, off);
                    s2 += __shfl_xor(s2, off);
                }
                float mu  = s1 * (1.f / 64.f);
                float var = s2 * (1.f / 64.f) - mu * mu;
                float rs  = rsqrtf(var + 1e-5f);
                int row = m0 + wr * 64 + i * 16 + quad * 4 + r;
#pragma unroll
                for (int j = 0; j < 4; j++) {
                    float v = ((acc[i][j][r] - mu) * rs * g[j] + bt[j]) * oscale;
                    out[(size_t)row * EE + n0 + wc * 64 + j * 16 + lr] = __float2bfloat16(v);
                }
            }
        }
    } else {
#pragma unroll
        for (int i = 0; i < 4; i++)
#pragma unroll
            for (int r = 0; r < 4; r++) {
                int row = m0 + wr * 64 + i * 16 + quad * 4 + r;
#pragma unroll
                for (int j = 0; j < 4; j++)
                    out[(size_t)row * EE + n0 + wc * 64 + j * 16 + lr] =
                        __float2bfloat16(acc[i][j][r]);
            }
    }
}

// ---------------------------------------------------------------------------
// Causal flash attention (unchanged from round 3).
// ---------------------------------------------------------------------------
__global__ __launch_bounds__(256) void flash(
    const bf16* __restrict__ Qb, const bf16* __restrict__ Kb,
    const bf16* __restrict__ Vb, bf16* __restrict__ Ob)
{
    const int pr = blockIdx.x;
    const int bh = blockIdx.y;
    const int b = bh >> 4, h = bh & 15;
    const int tid = threadIdx.x, lane = tid & 63, w = tid >> 6;
    const int lr = lane & 15, quad = lane >> 4;
    const size_t base = (size_t)b * 2048 * 1024 + h * 64;
    const float C = 1.44269504088896340736f;

    __shared__ __align__(16) short VT[64 * 72];
    __shared__ __align__(16) short PT[128 * 72];

#pragma unroll 1
    for (int ph = 0; ph < 2; ++ph) {
        const int qt = ph ? (15 - pr) : pr;
        const int tw = qt * 128 + w * 32;

        s16x8 qf[2][2];
#pragma unroll
        for (int i = 0; i < 2; i++)
#pragma unroll
            for (int ks = 0; ks < 2; ks++)
                qf[i][ks] = ld8(Qb + base + (size_t)(tw + i * 16 + lr) * 1024 +
                                ks * 32 + quad * 8);

        f32x4 o[2][4];
        float mrow[2], lrow[2];
#pragma unroll
        for (int i = 0; i < 2; i++) {
#pragma unroll
            for (int j = 0; j < 4; j++) o[i][j] = (f32x4){0.f, 0.f, 0.f, 0.f};
            mrow[i] = -1e30f;
            lrow[i] = 0.f;
        }

        const int nkt = 2 * qt + 2;
        for (int kt = 0; kt < nkt; ++kt) {
            const int kb = kt * 64;
            const bool active = (kb <= tw + 31);

            s16x8 v0 = ld8(Vb + base + (size_t)(kb + lane) * 1024 + w * 8);
            s16x8 v1 = ld8(Vb + base + (size_t)(kb + lane) * 1024 + w * 8 + 32);

            s16x8 kf[4][2];
            if (active) {
#pragma unroll
                for (int jk = 0; jk < 4; jk++)
#pragma unroll
                    for (int ks = 0; ks < 2; ks++)
                        kf[jk][ks] = ld8(Kb + base + (size_t)(kb + jk * 16 + lr) * 1024 +
                                         ks * 32 + quad * 8);
            }

            __syncthreads();
#pragma unroll
            for (int e = 0; e < 8; e++) {
                VT[(w * 8 + e) * 72 + lane]      = v0[e];
                VT[(w * 8 + 32 + e) * 72 + lane] = v1[e];
            }

            float a_bc[2][4];
            if (active) {
                f32x4 sc[2][4];
#pragma unroll
                for (int i = 0; i < 2; i++)
#pragma unroll
                    for (int jk = 0; jk < 4; jk++) sc[i][jk] = (f32x4){0.f, 0.f, 0.f, 0.f};
#pragma unroll
                for (int ks = 0; ks < 2; ks++)
#pragma unroll
                    for (int i = 0; i < 2; i++)
#pragma unroll
                        for (int jk = 0; jk < 4; jk++)
                            sc[i][jk] = MFMA16(kf[jk][ks], qf[i][ks], sc[i][jk]);

#pragma unroll
                for (int i = 0; i < 2; i++) {
                    const int qq = tw + i * 16 + lr;
                    float mx = -1e30f;
#pragma unroll
                    for (int jk = 0; jk < 4; jk++)
#pragma unroll
                        for (int r = 0; r < 4; r++) {
                            float zv = sc[i][jk][r] * C;
                            int key = kb + jk * 16 + quad * 4 + r;
                            if (key > qq) zv = -1e30f;
                            sc[i][jk][r] = zv;
                            mx = fmaxf(mx, zv);
                        }
                    mx = fmaxf(mx, __shfl_xor(mx, 16));
                    mx = fmaxf(mx, __shfl_xor(mx, 32));
                    float mn = fmaxf(mrow[i], mx);
                    float al = exp2f(mrow[i] - mn);
                    mrow[i] = mn;
                    float ps = 0.f;
#pragma unroll
                    for (int jk = 0; jk < 4; jk++)
#pragma unroll
                        for (int r = 0; r < 4; r++) {
                            float pv = exp2f(sc[i][jk][r] - mn);
                            sc[i][jk][r] = pv;
                            ps += pv;
                        }
                    ps += __shfl_xor(ps, 16);
                    ps += __shfl_xor(ps, 32);
                    lrow[i] = lrow[i] * al + ps;

                    short* prow = PT + (w * 32 + i * 16 + lr) * 72;
#pragma unroll
                    for (int jk = 0; jk < 4; jk++) {
                        s16x4 pk;
#pragma unroll
                        for (int r = 0; r < 4; r++)
                            pk[r] = __builtin_bit_cast(short, __float2bfloat16(sc[i][jk][r]));
                        *reinterpret_cast<s16x4*>(prow + jk * 16 + quad * 4) = pk;
                    }
#pragma unroll
                    for (int r = 0; r < 4; r++) a_bc[i][r] = __shfl(al, quad * 4 + r);
                }
            }

            __syncthreads();

            if (active) {
#pragma unroll
                for (int i = 0; i < 2; i++)
#pragma unroll
                    for (int j = 0; j < 4; j++)
#pragma unroll
                        for (int r = 0; r < 4; r++) o[i][j][r] *= a_bc[i][r];
#pragma unroll
                for (int ks = 0; ks < 2; ks++) {
                    s16x8 pf[2], vf[4];
#pragma unroll
                    for (int i = 0; i < 2; i++)
                        pf[i] = ld8s(PT + (w * 32 + i * 16 + lr) * 72 + ks * 32 + quad * 8);
#pragma unroll
                    for (int j = 0; j < 4; j++)
                        vf[j] = ld8s(VT + (j * 16 + lr) * 72 + ks * 32 + quad * 8);
#pragma unroll
                    for (int i = 0; i < 2; i++)
#pragma unroll
                        for (int j = 0; j < 4; j++) o[i][j] = MFMA16(pf[i], vf[j], o[i][j]);
                }
            }
        }

#pragma unroll
        for (int i = 0; i < 2; i++) {
            float lb[4];
#pragma unroll
            for (int r = 0; r < 4; r++) lb[r] = __shfl(lrow[i], quad * 4 + r);
#pragma unroll
            for (int r = 0; r < 4; r++) {
                float inv = 1.f / lb[r];
                int t = tw + i * 16 + quad * 4 + r;
#pragma unroll
                for (int j = 0; j < 4; j++)
                    Ob[base + (size_t)t * 1024 + j * 16 + lr] =
                        __float2bfloat16(o[i][j][r] * inv);
            }
        }
    }
}

// ---------------------------------------------------------------------------
// out = A @ Wu^T + bu  (m97 structure, both operands bf16 via global_load_lds)
// ---------------------------------------------------------------------------
__global__ __launch_bounds__(256) void gemm_bias(
    const bf16* __restrict__ A, const bf16* __restrict__ Bt,
    const float* __restrict__ bias, float* __restrict__ out)
{
    __shared__ __align__(16) short lA[128 * 32];
    __shared__ __align__(16) short lB[128 * 32];

    const int tid  = threadIdx.x;
    const int lane = tid & 63;
    const int w    = tid >> 6;
    const int wr = w >> 1, wc = w & 1;
    const int lr = lane & 15, quad = lane >> 4;

    const int m0 = blockIdx.y * 128;
    const int n0 = blockIdx.x * 128;

    const int strow = w * 32 + (lane >> 2);
    const int stcol = (lane & 3) * 8;
    const bf16* agl = A  + (size_t)(m0 + strow) * EE + stcol;
    const bf16* bgl = Bt + (size_t)(n0 + strow) * EE + stcol;
    short* al = lA + (w * 2) * 512;
    short* bl = lB + (w * 2) * 512;

    f32x4 acc[4][4];
#pragma unroll
    for (int i = 0; i < 4; i++)
#pragma unroll
        for (int j = 0; j < 4; j++) acc[i][j] = (f32x4){0.f, 0.f, 0.f, 0.f};

    const short* lArd = lA + (wr * 64 + lr) * 32 + quad * 8;
    const short* lBrd = lB + (wc * 64 + lr) * 32 + quad * 8;

    for (int kt = 0; kt < EE / 32; ++kt) {
        __syncthreads();
        async16(al, agl);
        async16(al + 512, agl + 16 * EE);
        async16(bl, bgl);
        async16(bl + 512, bgl + 16 * EE);
        agl += 32;
        bgl += 32;
        __syncthreads();

        s16x8 af[4], bfr[4];
#pragma unroll
        for (int i = 0; i < 4; i++) af[i]  = ld8s(lArd + i * 16 * 32);
#pragma unroll
        for (int j = 0; j < 4; j++) bfr[j] = ld8s(lBrd + j * 16 * 32);
#pragma unroll
        for (int i = 0; i < 4; i++)
#pragma unroll
            for (int j = 0; j < 4; j++) acc[i][j] = MFMA16(af[i], bfr[j], acc[i][j]);
    }

    float bz[4];
#pragma unroll
    for (int j = 0; j < 4; j++)
        bz[j] = bias[n0 + wc * 64 + j * 16 + lr];
#pragma unroll
    for (int i = 0; i < 4; i++)
#pragma unroll
        for (int r = 0; r < 4; r++) {
            int row = m0 + wr * 64 + i * 16 + quad * 4 + r;
#pragma unroll
            for (int j = 0; j < 4; j++)
                out[(size_t)row * EE + n0 + wc * 64 + j * 16 + lr] =
                    acc[i][j][r] + bz[j];
        }
}

// ---------------------------------------------------------------------------
extern "C" void kernel_launch(void* const* d_in, const int* in_sizes, int n_in,
                              void* d_out, int out_size, void* d_ws, size_t ws_size,
                              hipStream_t stream)
{
    (void)in_sizes; (void)n_in; (void)out_size;
    const float* x   = (const float*)d_in[0];
    const float* Wq  = (const float*)d_in[1];
    const float* Wk  = (const float*)d_in[2];
    const float* Wv  = (const float*)d_in[3];
    const float* Wu  = (const float*)d_in[4];
    const float* bu  = (const float*)d_in[5];
    const float* qg  = (const float*)d_in[6];
    const float* qbt = (const float*)d_in[7];
    const float* kg  = (const float*)d_in[8];
    const float* kbt = (const float*)d_in[9];
    float* out = (float*)d_out;

    bf16* Qb  = (bf16*)d_ws;                    // 16MB (doubles as attn-out)
    bf16* Kb  = Qb  + (size_t)8192 * 1024;
    bf16* Vb  = Kb  + (size_t)8192 * 1024;
    bf16* Wqb = Vb  + (size_t)8192 * 1024;      // 2MB each
    bf16* Wkb = Wqb + (size_t)1024 * 1024;
    bf16* Wvb = Wkb + (size_t)1024 * 1024;
    bf16* Wub = Wvb + (size_t)1024 * 1024;
    bf16* xb  = Wub + (size_t)1024 * 1024;      // 16MB

    const size_t need = ((size_t)3 * 8192 * 1024 + 4 * 1024 * 1024 + 8192 * 1024) * 2;
    const bool fast = ws_size >= need;

    cvt_all<<<dim3(512, 1, fast ? 12 : 4), 256, 0, stream>>>(
        Wq, Wk, Wv, Wu, x, Wqb, Wkb, Wvb, Wub, xb);
    if (fast)
        gemm_qkv_t<0><<<dim3(8, 64, 3), 256, 0, stream>>>(
            x, xb, Wqb, Wkb, Wvb, Qb, Kb, Vb, qg, qbt, kg, kbt);
    else
        gemm_qkv_t<1><<<dim3(8, 64, 3), 256, 0, stream>>>(
            x, nullptr, Wqb, Wkb, Wvb, Qb, Kb, Vb, qg, qbt, kg, kbt);
    flash<<<dim3(8, 64), 256, 0, stream>>>(Qb, Kb, Vb, Qb);
    gemm_bias<<<dim3(8, 64), 256, 0, stream>>>(Qb, Wub, bu, out);
}